// Round 12
// baseline (232.297 us; speedup 1.0000x reference)
//
#include <hip/hip_runtime.h>

// CouplingLayer: 4x conv3x3(SAME) + per-pixel 16x16 expm(A)@x2 + trace logdet.
// f16 MFMA (16x16x32), fp32 accum. Activations NHWC f16.
// conv0..2: 2 output rows/block, 512 thr, grid=512. conv3 fused with epilogue.
// R12: fix R11's MM bug (MM must = NCOG; was NCOG/2 -> half the pixels never
// computed -> stale LDS -> inf/NaN cascade). conv<128>: 2 co-groups x 4
// px-groups (NTW=4, MM=2) halves K-loop ds_read traffic. Taylor 18->10 terms.
// K-loop stays dy-rolled x12-unrolled (R10: full unroll = I-cache streaming).
// NOTE: no min-waves in launch_bounds (R6: forcing 4/EU spilled acc to scratch).

typedef _Float16 f16;
typedef _Float16 f16x8 __attribute__((ext_vector_type(8)));
typedef _Float16 f16x4 __attribute__((ext_vector_type(4)));
typedef float    f32x4 __attribute__((ext_vector_type(4)));

#define NPX 65536   // B*H*W

// workspace layout (bytes)
constexpr size_t OFF_X1A = 0;                       // 2 MB
constexpr size_t OFF_HA  = 2097152;                 // 16 MB
constexpr size_t OFF_HB  = OFF_HA  + 16777216;      // 16 MB
constexpr size_t OFF_W0P = OFF_HB  + 16777216;
constexpr size_t OFF_W1P = OFF_W0P + 40960;
constexpr size_t OFF_W2P = OFF_W1P + 294912;
constexpr size_t OFF_W3P = OFF_W2P + 294912;
// total ~35.6 MB

// DPP quad broadcast: all 4 lanes of a quad get lane (quad|S)'s value. Pure VALU.
template<int S>
__device__ __forceinline__ float qb(float v) {
  return __builtin_bit_cast(float, __builtin_amdgcn_mov_dpp(
      __builtin_bit_cast(int, v), S * 0x55, 0xF, 0xF, true));
}

// ---------------- setup: logdet zero, x1->NHWC f16, weight packs ----------------
template<int CI, int CO>
__device__ inline void pack_one(const float* __restrict__ w, f16* __restrict__ pk, int el) {
  constexpr int NT = CO / 16;
  int jj   = el & 7;
  int lane = (el >> 3) & 63;
  int ntkc = el >> 9;
  int nt   = ntkc % NT;
  int kc   = ntkc / NT;
  int k  = kc * 32 + (lane >> 4) * 8 + jj;
  int t  = k / CI;
  int ci = k % CI;
  int co = nt * 16 + (lane & 15);
  float v = 0.0f;
  if (t < 9) v = w[(size_t)(co * CI + ci) * 9 + t];
  pk[el] = (f16)v;
}

__global__ __launch_bounds__(256) void setup_k(
    const float* __restrict__ x,
    const float* __restrict__ w0, const float* __restrict__ w1,
    const float* __restrict__ w2, const float* __restrict__ w3,
    float* __restrict__ logdet,
    f16* __restrict__ x1a, f16* __restrict__ w0p, f16* __restrict__ w1p,
    f16* __restrict__ w2p, f16* __restrict__ w3p)
{
  int tid0 = blockIdx.x * 256 + threadIdx.x;
  int nth  = gridDim.x * 256;
  if (tid0 < 16) logdet[tid0] = 0.0f;
  // x1 -> NHWC f16
  for (int p = tid0; p < NPX; p += nth) {
    int n = p >> 12; int rem = p & 4095;
    const float* src = x + (size_t)n * 131072 + rem;
    f16x8 v0, v1;
#pragma unroll
    for (int c = 0; c < 8; ++c) v0[c] = (f16)src[(size_t)c * 4096];
#pragma unroll
    for (int c = 0; c < 8; ++c) v1[c] = (f16)src[(size_t)(c + 8) * 4096];
    *(f16x8*)&x1a[(size_t)p * 16]     = v0;
    *(f16x8*)&x1a[(size_t)p * 16 + 8] = v1;
  }
  for (int i = tid0; i < 5  * 8  * 512; i += nth) pack_one<16, 128>(w0, w0p, i);
  for (int i = tid0; i < 36 * 8  * 512; i += nth) pack_one<128,128>(w1, w1p, i);
  for (int i = tid0; i < 36 * 8  * 512; i += nth) pack_one<128,128>(w2, w2p, i);
  for (int i = tid0; i < 36 * 17 * 512; i += nth) pack_one<128,272>(w3, w3p, i);
}

// ---------------- conv3x3 SAME (CO=128), implicit GEMM, 2 rows per block ---------
// Wave split: CI=16 -> 4 co-groups x 2 px-groups (NTW=2, MM=4);
//             CI=128 -> 2 co-groups x 4 px-groups (NTW=4, MM=2) for A-load reuse.
template<int CI, bool ELU>
__global__ __launch_bounds__(512) void conv_k(
    const f16* __restrict__ in, const f16* __restrict__ wpk,
    const float* __restrict__ bias, f16* __restrict__ outp)
{
  constexpr int NT   = 8;                      // 128/16
  constexpr int NCOG = (CI == 16) ? 4 : 2;     // co-groups
  constexpr int NTW  = NT / NCOG;              // tiles per wave
  constexpr int MM   = NCOG;                   // m iters: px/wave = 16*NCOG
  constexpr int ROWB = (CI == 16) ? 48 : 272;
  constexpr int NROW = (CI == 16) ? 5 : 4;
  constexpr int CPL  = CI / 8;

  extern __shared__ __align__(16) char smem[];

  const int tid  = threadIdx.x;
  const int wave = tid >> 6;
  const int lane = tid & 63;
  const int g    = lane >> 4;
  const int r15  = lane & 15;
  const int wq   = wave % NCOG;
  const int mg   = wave / NCOG;
  const int blk  = blockIdx.x;
  const int n    = blk >> 5;
  const int y0   = (blk & 31) * 2;

  for (int it = tid; it < 4 * 64 * CPL; it += 512) {
    int c8   = it % CPL;
    int xcol = (it / CPL) & 63;
    int r    = it / (64 * CPL);
    int yy   = y0 + r - 1;
    f16x8 v = {};
    if (yy >= 0 && yy < 64)
      v = *(const f16x8*)&in[((size_t)((n * 64 + yy) * 64 + xcol)) * CI + c8 * 8];
    int xl = xcol + 1;
    *(f16x8*)(smem + (r * 66 + xl) * ROWB + c8 * 16) = v;
  }
  for (int it = tid; it < NROW * 2 * CPL; it += 512) {
    int c8   = it % CPL;
    int side = (it / CPL) & 1;
    int r    = it / (2 * CPL);
    int xl   = side ? 65 : 0;
    *(f16x8*)(smem + (r * 66 + xl) * ROWB + c8 * 16) = f16x8{};
  }
  if (CI == 16) {
    for (int it = tid; it < 64 * CPL; it += 512) {
      int c8 = it % CPL;
      int xl = it / CPL + 1;
      *(f16x8*)(smem + (4 * 66 + xl) * ROWB + c8 * 16) = f16x8{};
    }
  }
  __syncthreads();

  const int nt0 = wq * NTW;

  f32x4 acc[MM][NTW];
#pragma unroll
  for (int m = 0; m < MM; ++m)
#pragma unroll
    for (int w = 0; w < NTW; ++w) acc[m][w] = f32x4{0.f, 0.f, 0.f, 0.f};

  // A-side base (one VGPR; per-(kc,m) offsets are immediates for CI=128)
  const char* abase;
  if constexpr (CI == 16)
    abase = smem + (mg * 66 + r15) * ROWB;           // mg in 0..1: row half
  else
    abase = smem + ((mg >> 1) * 66 + (mg & 1) * 32 + r15) * ROWB + g * 16;  // mg in 0..3

  const f16* bp[NTW];
#pragma unroll
  for (int w = 0; w < NTW; ++w)
    bp[w] = wpk + ((size_t)(nt0 + w) * 64 + lane) * 8;

  f16x8 bb[2][NTW];
#pragma unroll
  for (int w = 0; w < NTW; ++w) { bb[0][w] = *(const f16x8*)bp[w]; bp[w] += NT * 512; }

  if constexpr (CI == 16) {
#pragma unroll
    for (int kc = 0; kc < 5; ++kc) {
      if (kc + 1 < 5) {
#pragma unroll
        for (int w = 0; w < NTW; ++w) { bb[(kc + 1) & 1][w] = *(const f16x8*)bp[w]; bp[w] += NT * 512; }
      }
      int k0  = kc * 32 + g * 8;
      int t   = k0 >> 4;
      int ci  = k0 & 15;
      int dy  = t / 3;
      int dxm = t - 3 * dy;
      int rr  = (dy == 3) ? (4 - mg) : dy;   // padded taps -> zero row (abs row 4)
      int off = rr * 66 * ROWB + dxm * ROWB + ci * 2;
      f16x8 a[MM];
#pragma unroll
      for (int m = 0; m < MM; ++m)
        a[m] = *(const f16x8*)(abase + m * 16 * ROWB + off);
#pragma unroll
      for (int w = 0; w < NTW; ++w)
#pragma unroll
        for (int m = 0; m < MM; ++m)
          acc[m][w] = __builtin_amdgcn_mfma_f32_16x16x32_f16(a[m], bb[kc & 1][w], acc[m][w], 0, 0, 0);
    }
  } else {
    const char* ab = abase;
    for (int dy = 0; dy < 3; ++dy) {
#pragma unroll
      for (int j = 0; j < 12; ++j) {
        if (j < 11 || dy < 2) {
#pragma unroll
          for (int w = 0; w < NTW; ++w) { bb[(j + 1) & 1][w] = *(const f16x8*)bp[w]; bp[w] += NT * 512; }
        }
        f16x8 a[MM];
#pragma unroll
        for (int m = 0; m < MM; ++m)
          a[m] = *(const f16x8*)(ab + m * 16 * ROWB + (j / 4) * ROWB + (j % 4) * 64);
#pragma unroll
        for (int w = 0; w < NTW; ++w)
#pragma unroll
          for (int m = 0; m < MM; ++m)
            acc[m][w] = __builtin_amdgcn_mfma_f32_16x16x32_f16(a[m], bb[j & 1][w], acc[m][w], 0, 0, 0);
      }
      ab += 66 * ROWB;
    }
  }

  // stage f16 NHWC tile [128 px][128 co] (XOR-swizzled), linear copy-out
  __syncthreads();
#pragma unroll
  for (int w = 0; w < NTW; ++w)
#pragma unroll
    for (int m = 0; m < MM; ++m)
#pragma unroll
      for (int e = 0; e < 4; ++e) {
        int px = mg * (16 * MM) + m * 16 + g * 4 + e;
        int co = (nt0 + w) * 16 + r15;
        float v = acc[m][w][e] + bias[co];
        if (ELU) v = v > 0.f ? v : exp2f(v * 1.442695041f) - 1.0f;
        *(f16*)(smem + px * 256 + ((co * 2) ^ ((px & 7) << 5))) = (f16)v;
      }
  __syncthreads();
  for (int i = tid; i < 2048; i += 512) {
    int px = i >> 4, c = i & 15;
    f16x8 v = *(const f16x8*)(smem + px * 256 + ((c * 16) ^ ((px & 7) << 5)));
    *(f16x8*)&outp[(size_t)blk * 16384 + (size_t)i * 8] = v;
  }
}

// ---------------- conv3 + epilogue, fused -------------------------------------
__global__ __launch_bounds__(512) void conv3epi_k(
    const f16* __restrict__ in, const f16* __restrict__ wpk,
    const float* __restrict__ bias, const float* __restrict__ x,
    const float* __restrict__ sc_, const float* __restrict__ sp_,
    const float* __restrict__ rs_, const float* __restrict__ rsh_,
    float* __restrict__ out, float* __restrict__ logdet)
{
  constexpr int NT = 17, NTW = 5, ROWB = 272;

  extern __shared__ __align__(16) char smem[];

  const int tid  = threadIdx.x;
  const int wave = tid >> 6;
  const int lane = tid & 63;
  const int g    = lane >> 4;
  const int r15  = lane & 15;
  const int mg   = wave >> 2;
  const int wq   = wave & 3;
  const int blk  = blockIdx.x;
  const int n    = blk >> 5;
  const int y0   = (blk & 31) * 2;

  for (int it = tid; it < 4 * 64 * 16; it += 512) {
    int c8   = it & 15;
    int xcol = (it >> 4) & 63;
    int r    = it >> 10;
    int yy   = y0 + r - 1;
    f16x8 v = {};
    if (yy >= 0 && yy < 64)
      v = *(const f16x8*)&in[((size_t)((n * 64 + yy) * 64 + xcol)) * 128 + c8 * 8];
    int xl = xcol + 1;
    *(f16x8*)(smem + (r * 66 + xl) * ROWB + c8 * 16) = v;
  }
  for (int it = tid; it < 4 * 2 * 16; it += 512) {
    int c8   = it & 15;
    int side = (it >> 4) & 1;
    int r    = it >> 5;
    int xl   = side ? 65 : 0;
    *(f16x8*)(smem + (r * 66 + xl) * ROWB + c8 * 16) = f16x8{};
  }
  __syncthreads();

  // co split {5,4,4,4}
  const int ncnt = (wq == 0) ? 5 : 4;
  const int nt0  = (wq == 0) ? 0 : 4 * wq + 1;

  f32x4 acc[4][NTW];
#pragma unroll
  for (int m = 0; m < 4; ++m)
#pragma unroll
    for (int w = 0; w < NTW; ++w) acc[m][w] = f32x4{0.f, 0.f, 0.f, 0.f};

  const char* abase = smem + (mg * 66 + r15) * ROWB + g * 16;
  const f16* bp[NTW];
#pragma unroll
  for (int w = 0; w < NTW; ++w)
    bp[w] = wpk + ((size_t)(nt0 + w) * 64 + lane) * 8;

  f16x8 bb[2][NTW];
#pragma unroll
  for (int w = 0; w < NTW; ++w) {
    if (w < ncnt) bb[0][w] = *(const f16x8*)bp[w];
    bp[w] += NT * 512;
  }

  {
    const char* ab = abase;
    for (int dy = 0; dy < 3; ++dy) {
#pragma unroll
      for (int j = 0; j < 12; ++j) {
        if (j < 11 || dy < 2) {
#pragma unroll
          for (int w = 0; w < NTW; ++w) {
            if (w < ncnt) bb[(j + 1) & 1][w] = *(const f16x8*)bp[w];
            bp[w] += NT * 512;
          }
        }
        f16x8 a[4];
#pragma unroll
        for (int m = 0; m < 4; ++m)
          a[m] = *(const f16x8*)(ab + m * 16 * ROWB + (j / 4) * ROWB + (j % 4) * 64);
#pragma unroll
        for (int w = 0; w < NTW; ++w) {
          if (w < ncnt) {
#pragma unroll
            for (int m = 0; m < 4; ++m)
              acc[m][w] = __builtin_amdgcn_mfma_f32_16x16x32_f16(a[m], bb[j & 1][w], acc[m][w], 0, 0, 0);
          }
        }
      }
      ab += 66 * ROWB;
    }
  }

  // phase 3: o-tile -> LDS, rows of 560 B
  __syncthreads();
#pragma unroll
  for (int w = 0; w < NTW; ++w) {
    if (w < ncnt) {
#pragma unroll
      for (int m = 0; m < 4; ++m)
#pragma unroll
        for (int e = 0; e < 4; ++e) {
          int px = mg * 64 + m * 16 + g * 4 + e;
          int co = (nt0 + w) * 16 + r15;
          *(f16*)(smem + px * 560 + co * 2) = (f16)(acc[m][w][e] + bias[co]);
        }
    }
  }
  __syncthreads();

  // phase 4: epilogue. 4 lanes per pixel.
  {
    const int px  = tid >> 2;
    const int sub = tid & 3;
    const char* row = smem + px * 560;
    const float sc = *sc_, sp = *sp_, rs = *rs_, rsh = *rsh_;

    float A[16][4];
    float tr = 0.0f;
#pragma unroll
    for (int j = 0; j < 16; ++j) {
      f16x4 hv = *(const f16x4*)(row + 32 + 32 * j + 8 * sub);
#pragma unroll
      for (int k = 0; k < 4; ++k) {
        float z = sc * (float)hv[k] + sp;
        float e = exp2f(z * 2.885390082f);
        float a = rs * (1.0f - 2.0f * __builtin_amdgcn_rcpf(e + 1.0f)) + rsh;
        A[j][k] = a;
        if (sub == (j >> 2) && k == (j & 3)) tr += a;
      }
    }
    f16x4 shv = *(const f16x4*)(row + 8 * sub);

    const size_t pixoff = (size_t)n * 131072 + (size_t)y0 * 64 + px;
    float xv[4];
#pragma unroll
    for (int k = 0; k < 4; ++k)
      xv[k] = x[pixoff + (size_t)(16 + 4 * sub + k) * 4096];
#pragma unroll
    for (int k = 0; k < 4; ++k)
      out[pixoff + (size_t)(4 * sub + k) * 4096] = x[pixoff + (size_t)(4 * sub + k) * 4096];

    // Taylor-10: ||A||inf <= 16*(1/16)*tanh <= 1 -> tail Sum_{11..18} 1/k! ~ 2.7e-8
    float t0 = xv[0], t1 = xv[1], t2 = xv[2], t3 = xv[3];
    float a0 = xv[0], a1 = xv[1], a2 = xv[2], a3 = xv[3];
#pragma unroll
    for (int it = 1; it <= 10; ++it) {
      float ya[16];
      ya[0]  = qb<0>(t0); ya[1]  = qb<0>(t1); ya[2]  = qb<0>(t2); ya[3]  = qb<0>(t3);
      ya[4]  = qb<1>(t0); ya[5]  = qb<1>(t1); ya[6]  = qb<1>(t2); ya[7]  = qb<1>(t3);
      ya[8]  = qb<2>(t0); ya[9]  = qb<2>(t1); ya[10] = qb<2>(t2); ya[11] = qb<2>(t3);
      ya[12] = qb<3>(t0); ya[13] = qb<3>(t1); ya[14] = qb<3>(t2); ya[15] = qb<3>(t3);
      float n0 = 0.f, n1 = 0.f, n2 = 0.f, n3 = 0.f;
#pragma unroll
      for (int j = 0; j < 16; ++j) {
        n0 += A[j][0] * ya[j];
        n1 += A[j][1] * ya[j];
        n2 += A[j][2] * ya[j];
        n3 += A[j][3] * ya[j];
      }
      const float inv = 1.0f / (float)it;
      t0 = n0 * inv; t1 = n1 * inv; t2 = n2 * inv; t3 = n3 * inv;
      a0 += t0; a1 += t1; a2 += t2; a3 += t3;
    }
    out[pixoff + (size_t)(16 + 4 * sub + 0) * 4096] = a0 + (float)shv[0];
    out[pixoff + (size_t)(16 + 4 * sub + 1) * 4096] = a1 + (float)shv[1];
    out[pixoff + (size_t)(16 + 4 * sub + 2) * 4096] = a2 + (float)shv[2];
    out[pixoff + (size_t)(16 + 4 * sub + 3) * 4096] = a3 + (float)shv[3];

    // logdet: wave reduce -> LDS partials -> 1 atomic per block
    float tt = tr + __shfl_xor(tr, 1, 64);
    tt += __shfl_xor(tt, 2, 64);
    tt += __shfl_xor(tt, 4, 64);
    tt += __shfl_xor(tt, 8, 64);
    tt += __shfl_xor(tt, 16, 64);
    tt += __shfl_xor(tt, 32, 64);
    float* part = (float*)(smem + 71680);   // past the 128x560 o-tile
    if (lane == 0) part[wave] = tt;
    __syncthreads();
    if (tid == 0) {
      float s = part[0] + part[1] + part[2] + part[3]
              + part[4] + part[5] + part[6] + part[7];
      atomicAdd(&logdet[n], s);
    }
  }
}

extern "C" void kernel_launch(void* const* d_in, const int* in_sizes, int n_in,
                              void* d_out, int out_size, void* d_ws, size_t ws_size,
                              hipStream_t stream) {
  const float* x   = (const float*)d_in[0];
  const float* sc  = (const float*)d_in[1];
  const float* sp  = (const float*)d_in[2];
  const float* rs  = (const float*)d_in[3];
  const float* rsh = (const float*)d_in[4];
  const float* w0  = (const float*)d_in[5];
  const float* b0  = (const float*)d_in[6];
  const float* w1  = (const float*)d_in[7];
  const float* b1  = (const float*)d_in[8];
  const float* w2  = (const float*)d_in[9];
  const float* b2  = (const float*)d_in[10];
  const float* w3  = (const float*)d_in[11];
  const float* b3  = (const float*)d_in[12];

  float* out    = (float*)d_out;
  float* logdet = out + 2097152;
  char* ws = (char*)d_ws;
  f16* x1a = (f16*)(ws + OFF_X1A);
  f16* hA  = (f16*)(ws + OFF_HA);
  f16* hB  = (f16*)(ws + OFF_HB);
  f16* w0p = (f16*)(ws + OFF_W0P);
  f16* w1p = (f16*)(ws + OFF_W1P);
  f16* w2p = (f16*)(ws + OFF_W2P);
  f16* w3p = (f16*)(ws + OFF_W3P);

  setup_k<<<1024, 256, 0, stream>>>(x, w0, w1, w2, w3, logdet, x1a, w0p, w1p, w2p, w3p);
  conv_k<16,  true><<<512, 512, 32768, stream>>>(x1a, w0p, b0, hA);
  conv_k<128, true><<<512, 512, 71808, stream>>>(hA, w1p, b1, hB);
  conv_k<128, true><<<512, 512, 71808, stream>>>(hB, w2p, b2, hA);
  conv3epi_k<<<512, 512, 71808, stream>>>(hA, w3p, b3, x, sc, sp, rs, rsh, out, logdet);
}

// Round 13
// 209.275 us; speedup vs baseline: 1.1100x; 1.1100x over previous
//
#include <hip/hip_runtime.h>

// CouplingLayer: 4x conv3x3(SAME) + per-pixel 16x16 expm(A)@x2 + trace logdet.
// f16 MFMA (16x16x32), fp32 accum. Activations NHWC f16.
// conv0..2: 2 output rows/block, 512 thr, grid=512. conv3 fused with epilogue.
// R13: conv_k reverted to R10 geometry (4 co-groups x 2 px-groups; R12's
// 2-co-group split doubled per-wave B global loads -> conv1/2 regressed).
// Keep R12's validated wins: Taylor-10 epilogue + block-reduced logdet.
// K-loop stays dy-rolled x12-unrolled (R10: full unroll = I-cache streaming).
// NOTE: no min-waves in launch_bounds (R6: forcing 4/EU spilled acc to scratch).

typedef _Float16 f16;
typedef _Float16 f16x8 __attribute__((ext_vector_type(8)));
typedef _Float16 f16x4 __attribute__((ext_vector_type(4)));
typedef float    f32x4 __attribute__((ext_vector_type(4)));

#define NPX 65536   // B*H*W

// workspace layout (bytes)
constexpr size_t OFF_X1A = 0;                       // 2 MB
constexpr size_t OFF_HA  = 2097152;                 // 16 MB
constexpr size_t OFF_HB  = OFF_HA  + 16777216;      // 16 MB
constexpr size_t OFF_W0P = OFF_HB  + 16777216;
constexpr size_t OFF_W1P = OFF_W0P + 40960;
constexpr size_t OFF_W2P = OFF_W1P + 294912;
constexpr size_t OFF_W3P = OFF_W2P + 294912;
// total ~35.6 MB

// DPP quad broadcast: all 4 lanes of a quad get lane (quad|S)'s value. Pure VALU.
template<int S>
__device__ __forceinline__ float qb(float v) {
  return __builtin_bit_cast(float, __builtin_amdgcn_mov_dpp(
      __builtin_bit_cast(int, v), S * 0x55, 0xF, 0xF, true));
}

// ---------------- setup: logdet zero, x1->NHWC f16, weight packs ----------------
template<int CI, int CO>
__device__ inline void pack_one(const float* __restrict__ w, f16* __restrict__ pk, int el) {
  constexpr int NT = CO / 16;
  int jj   = el & 7;
  int lane = (el >> 3) & 63;
  int ntkc = el >> 9;
  int nt   = ntkc % NT;
  int kc   = ntkc / NT;
  int k  = kc * 32 + (lane >> 4) * 8 + jj;
  int t  = k / CI;
  int ci = k % CI;
  int co = nt * 16 + (lane & 15);
  float v = 0.0f;
  if (t < 9) v = w[(size_t)(co * CI + ci) * 9 + t];
  pk[el] = (f16)v;
}

__global__ __launch_bounds__(256) void setup_k(
    const float* __restrict__ x,
    const float* __restrict__ w0, const float* __restrict__ w1,
    const float* __restrict__ w2, const float* __restrict__ w3,
    float* __restrict__ logdet,
    f16* __restrict__ x1a, f16* __restrict__ w0p, f16* __restrict__ w1p,
    f16* __restrict__ w2p, f16* __restrict__ w3p)
{
  int tid0 = blockIdx.x * 256 + threadIdx.x;
  int nth  = gridDim.x * 256;
  if (tid0 < 16) logdet[tid0] = 0.0f;
  // x1 -> NHWC f16
  for (int p = tid0; p < NPX; p += nth) {
    int n = p >> 12; int rem = p & 4095;
    const float* src = x + (size_t)n * 131072 + rem;
    f16x8 v0, v1;
#pragma unroll
    for (int c = 0; c < 8; ++c) v0[c] = (f16)src[(size_t)c * 4096];
#pragma unroll
    for (int c = 0; c < 8; ++c) v1[c] = (f16)src[(size_t)(c + 8) * 4096];
    *(f16x8*)&x1a[(size_t)p * 16]     = v0;
    *(f16x8*)&x1a[(size_t)p * 16 + 8] = v1;
  }
  for (int i = tid0; i < 5  * 8  * 512; i += nth) pack_one<16, 128>(w0, w0p, i);
  for (int i = tid0; i < 36 * 8  * 512; i += nth) pack_one<128,128>(w1, w1p, i);
  for (int i = tid0; i < 36 * 8  * 512; i += nth) pack_one<128,128>(w2, w2p, i);
  for (int i = tid0; i < 36 * 17 * 512; i += nth) pack_one<128,272>(w3, w3p, i);
}

// ---------------- conv3x3 SAME (CO=128), implicit GEMM, 2 rows per block ---------
// R10 geometry: 4 co-groups x 2 px-groups; NTW=2, MM=4 (px/wave = 64).
template<int CI, bool ELU>
__global__ __launch_bounds__(512) void conv_k(
    const f16* __restrict__ in, const f16* __restrict__ wpk,
    const float* __restrict__ bias, f16* __restrict__ outp)
{
  constexpr int NT   = 8;                      // 128/16
  constexpr int NTW  = 2;                      // co tiles per wave
  constexpr int ROWB = (CI == 16) ? 48 : 272;
  constexpr int NROW = (CI == 16) ? 5 : 4;
  constexpr int CPL  = CI / 8;

  extern __shared__ __align__(16) char smem[];

  const int tid  = threadIdx.x;
  const int wave = tid >> 6;
  const int lane = tid & 63;
  const int g    = lane >> 4;
  const int r15  = lane & 15;
  const int mg   = wave >> 2;                  // px-group (row half)
  const int wq   = wave & 3;                   // co-group
  const int blk  = blockIdx.x;
  const int n    = blk >> 5;
  const int y0   = (blk & 31) * 2;

  for (int it = tid; it < 4 * 64 * CPL; it += 512) {
    int c8   = it % CPL;
    int xcol = (it / CPL) & 63;
    int r    = it / (64 * CPL);
    int yy   = y0 + r - 1;
    f16x8 v = {};
    if (yy >= 0 && yy < 64)
      v = *(const f16x8*)&in[((size_t)((n * 64 + yy) * 64 + xcol)) * CI + c8 * 8];
    int xl = xcol + 1;
    *(f16x8*)(smem + (r * 66 + xl) * ROWB + c8 * 16) = v;
  }
  for (int it = tid; it < NROW * 2 * CPL; it += 512) {
    int c8   = it % CPL;
    int side = (it / CPL) & 1;
    int r    = it / (2 * CPL);
    int xl   = side ? 65 : 0;
    *(f16x8*)(smem + (r * 66 + xl) * ROWB + c8 * 16) = f16x8{};
  }
  if (CI == 16) {
    for (int it = tid; it < 64 * CPL; it += 512) {
      int c8 = it % CPL;
      int xl = it / CPL + 1;
      *(f16x8*)(smem + (4 * 66 + xl) * ROWB + c8 * 16) = f16x8{};
    }
  }
  __syncthreads();

  const int nt0 = wq * NTW;

  f32x4 acc[4][NTW];
#pragma unroll
  for (int m = 0; m < 4; ++m)
#pragma unroll
    for (int w = 0; w < NTW; ++w) acc[m][w] = f32x4{0.f, 0.f, 0.f, 0.f};

  // A-side base (one VGPR; per-(kc,m) offsets are immediates for CI=128)
  const char* abase = smem + (mg * 66 + r15) * ROWB + ((CI == 128) ? g * 16 : 0);
  const f16* bp[NTW];
#pragma unroll
  for (int w = 0; w < NTW; ++w)
    bp[w] = wpk + ((size_t)(nt0 + w) * 64 + lane) * 8;

  f16x8 bb[2][NTW];
#pragma unroll
  for (int w = 0; w < NTW; ++w) { bb[0][w] = *(const f16x8*)bp[w]; bp[w] += NT * 512; }

  if constexpr (CI == 16) {
#pragma unroll
    for (int kc = 0; kc < 5; ++kc) {
      if (kc + 1 < 5) {
#pragma unroll
        for (int w = 0; w < NTW; ++w) { bb[(kc + 1) & 1][w] = *(const f16x8*)bp[w]; bp[w] += NT * 512; }
      }
      int k0  = kc * 32 + g * 8;
      int t   = k0 >> 4;
      int ci  = k0 & 15;
      int dy  = t / 3;
      int dxm = t - 3 * dy;
      int rr  = (dy == 3) ? (4 - mg) : dy;   // padded taps -> zero row (abs row 4)
      int off = rr * 66 * ROWB + dxm * ROWB + ci * 2;
      f16x8 a[4];
#pragma unroll
      for (int m = 0; m < 4; ++m)
        a[m] = *(const f16x8*)(abase + m * 16 * ROWB + off);
#pragma unroll
      for (int w = 0; w < NTW; ++w)
#pragma unroll
        for (int m = 0; m < 4; ++m)
          acc[m][w] = __builtin_amdgcn_mfma_f32_16x16x32_f16(a[m], bb[kc & 1][w], acc[m][w], 0, 0, 0);
    }
  } else {
    const char* ab = abase;
    for (int dy = 0; dy < 3; ++dy) {
#pragma unroll
      for (int j = 0; j < 12; ++j) {
        if (j < 11 || dy < 2) {
#pragma unroll
          for (int w = 0; w < NTW; ++w) { bb[(j + 1) & 1][w] = *(const f16x8*)bp[w]; bp[w] += NT * 512; }
        }
        f16x8 a[4];
#pragma unroll
        for (int m = 0; m < 4; ++m)
          a[m] = *(const f16x8*)(ab + m * 16 * ROWB + (j / 4) * ROWB + (j % 4) * 64);
#pragma unroll
        for (int w = 0; w < NTW; ++w)
#pragma unroll
          for (int m = 0; m < 4; ++m)
            acc[m][w] = __builtin_amdgcn_mfma_f32_16x16x32_f16(a[m], bb[j & 1][w], acc[m][w], 0, 0, 0);
      }
      ab += 66 * ROWB;
    }
  }

  // stage f16 NHWC tile [128 px][128 co] (XOR-swizzled), linear copy-out
  __syncthreads();
#pragma unroll
  for (int w = 0; w < NTW; ++w)
#pragma unroll
    for (int m = 0; m < 4; ++m)
#pragma unroll
      for (int e = 0; e < 4; ++e) {
        int px = mg * 64 + m * 16 + g * 4 + e;
        int co = (nt0 + w) * 16 + r15;
        float v = acc[m][w][e] + bias[co];
        if (ELU) v = v > 0.f ? v : exp2f(v * 1.442695041f) - 1.0f;
        *(f16*)(smem + px * 256 + ((co * 2) ^ ((px & 7) << 5))) = (f16)v;
      }
  __syncthreads();
  for (int i = tid; i < 2048; i += 512) {
    int px = i >> 4, c = i & 15;
    f16x8 v = *(const f16x8*)(smem + px * 256 + ((c * 16) ^ ((px & 7) << 5)));
    *(f16x8*)&outp[(size_t)blk * 16384 + (size_t)i * 8] = v;
  }
}

// ---------------- conv3 + epilogue, fused -------------------------------------
__global__ __launch_bounds__(512) void conv3epi_k(
    const f16* __restrict__ in, const f16* __restrict__ wpk,
    const float* __restrict__ bias, const float* __restrict__ x,
    const float* __restrict__ sc_, const float* __restrict__ sp_,
    const float* __restrict__ rs_, const float* __restrict__ rsh_,
    float* __restrict__ out, float* __restrict__ logdet)
{
  constexpr int NT = 17, NTW = 5, ROWB = 272;

  extern __shared__ __align__(16) char smem[];

  const int tid  = threadIdx.x;
  const int wave = tid >> 6;
  const int lane = tid & 63;
  const int g    = lane >> 4;
  const int r15  = lane & 15;
  const int mg   = wave >> 2;
  const int wq   = wave & 3;
  const int blk  = blockIdx.x;
  const int n    = blk >> 5;
  const int y0   = (blk & 31) * 2;

  for (int it = tid; it < 4 * 64 * 16; it += 512) {
    int c8   = it & 15;
    int xcol = (it >> 4) & 63;
    int r    = it >> 10;
    int yy   = y0 + r - 1;
    f16x8 v = {};
    if (yy >= 0 && yy < 64)
      v = *(const f16x8*)&in[((size_t)((n * 64 + yy) * 64 + xcol)) * 128 + c8 * 8];
    int xl = xcol + 1;
    *(f16x8*)(smem + (r * 66 + xl) * ROWB + c8 * 16) = v;
  }
  for (int it = tid; it < 4 * 2 * 16; it += 512) {
    int c8   = it & 15;
    int side = (it >> 4) & 1;
    int r    = it >> 5;
    int xl   = side ? 65 : 0;
    *(f16x8*)(smem + (r * 66 + xl) * ROWB + c8 * 16) = f16x8{};
  }
  __syncthreads();

  // co split {5,4,4,4}
  const int ncnt = (wq == 0) ? 5 : 4;
  const int nt0  = (wq == 0) ? 0 : 4 * wq + 1;

  f32x4 acc[4][NTW];
#pragma unroll
  for (int m = 0; m < 4; ++m)
#pragma unroll
    for (int w = 0; w < NTW; ++w) acc[m][w] = f32x4{0.f, 0.f, 0.f, 0.f};

  const char* abase = smem + (mg * 66 + r15) * ROWB + g * 16;
  const f16* bp[NTW];
#pragma unroll
  for (int w = 0; w < NTW; ++w)
    bp[w] = wpk + ((size_t)(nt0 + w) * 64 + lane) * 8;

  f16x8 bb[2][NTW];
#pragma unroll
  for (int w = 0; w < NTW; ++w) {
    if (w < ncnt) bb[0][w] = *(const f16x8*)bp[w];
    bp[w] += NT * 512;
  }

  {
    const char* ab = abase;
    for (int dy = 0; dy < 3; ++dy) {
#pragma unroll
      for (int j = 0; j < 12; ++j) {
        if (j < 11 || dy < 2) {
#pragma unroll
          for (int w = 0; w < NTW; ++w) {
            if (w < ncnt) bb[(j + 1) & 1][w] = *(const f16x8*)bp[w];
            bp[w] += NT * 512;
          }
        }
        f16x8 a[4];
#pragma unroll
        for (int m = 0; m < 4; ++m)
          a[m] = *(const f16x8*)(ab + m * 16 * ROWB + (j / 4) * ROWB + (j % 4) * 64);
#pragma unroll
        for (int w = 0; w < NTW; ++w) {
          if (w < ncnt) {
#pragma unroll
            for (int m = 0; m < 4; ++m)
              acc[m][w] = __builtin_amdgcn_mfma_f32_16x16x32_f16(a[m], bb[j & 1][w], acc[m][w], 0, 0, 0);
          }
        }
      }
      ab += 66 * ROWB;
    }
  }

  // phase 3: o-tile -> LDS, rows of 560 B
  __syncthreads();
#pragma unroll
  for (int w = 0; w < NTW; ++w) {
    if (w < ncnt) {
#pragma unroll
      for (int m = 0; m < 4; ++m)
#pragma unroll
        for (int e = 0; e < 4; ++e) {
          int px = mg * 64 + m * 16 + g * 4 + e;
          int co = (nt0 + w) * 16 + r15;
          *(f16*)(smem + px * 560 + co * 2) = (f16)(acc[m][w][e] + bias[co]);
        }
    }
  }
  __syncthreads();

  // phase 4: epilogue. 4 lanes per pixel.
  {
    const int px  = tid >> 2;
    const int sub = tid & 3;
    const char* row = smem + px * 560;
    const float sc = *sc_, sp = *sp_, rs = *rs_, rsh = *rsh_;

    float A[16][4];
    float tr = 0.0f;
#pragma unroll
    for (int j = 0; j < 16; ++j) {
      f16x4 hv = *(const f16x4*)(row + 32 + 32 * j + 8 * sub);
#pragma unroll
      for (int k = 0; k < 4; ++k) {
        float z = sc * (float)hv[k] + sp;
        float e = exp2f(z * 2.885390082f);
        float a = rs * (1.0f - 2.0f * __builtin_amdgcn_rcpf(e + 1.0f)) + rsh;
        A[j][k] = a;
        if (sub == (j >> 2) && k == (j & 3)) tr += a;
      }
    }
    f16x4 shv = *(const f16x4*)(row + 8 * sub);

    const size_t pixoff = (size_t)n * 131072 + (size_t)y0 * 64 + px;
    float xv[4];
#pragma unroll
    for (int k = 0; k < 4; ++k)
      xv[k] = x[pixoff + (size_t)(16 + 4 * sub + k) * 4096];
#pragma unroll
    for (int k = 0; k < 4; ++k)
      out[pixoff + (size_t)(4 * sub + k) * 4096] = x[pixoff + (size_t)(4 * sub + k) * 4096];

    // Taylor-10: ||A||inf <= 16*(1/16)*tanh <= 1 -> tail Sum_{11..18} 1/k! ~ 2.7e-8
    float t0 = xv[0], t1 = xv[1], t2 = xv[2], t3 = xv[3];
    float a0 = xv[0], a1 = xv[1], a2 = xv[2], a3 = xv[3];
#pragma unroll
    for (int it = 1; it <= 10; ++it) {
      float ya[16];
      ya[0]  = qb<0>(t0); ya[1]  = qb<0>(t1); ya[2]  = qb<0>(t2); ya[3]  = qb<0>(t3);
      ya[4]  = qb<1>(t0); ya[5]  = qb<1>(t1); ya[6]  = qb<1>(t2); ya[7]  = qb<1>(t3);
      ya[8]  = qb<2>(t0); ya[9]  = qb<2>(t1); ya[10] = qb<2>(t2); ya[11] = qb<2>(t3);
      ya[12] = qb<3>(t0); ya[13] = qb<3>(t1); ya[14] = qb<3>(t2); ya[15] = qb<3>(t3);
      float n0 = 0.f, n1 = 0.f, n2 = 0.f, n3 = 0.f;
#pragma unroll
      for (int j = 0; j < 16; ++j) {
        n0 += A[j][0] * ya[j];
        n1 += A[j][1] * ya[j];
        n2 += A[j][2] * ya[j];
        n3 += A[j][3] * ya[j];
      }
      const float inv = 1.0f / (float)it;
      t0 = n0 * inv; t1 = n1 * inv; t2 = n2 * inv; t3 = n3 * inv;
      a0 += t0; a1 += t1; a2 += t2; a3 += t3;
    }
    out[pixoff + (size_t)(16 + 4 * sub + 0) * 4096] = a0 + (float)shv[0];
    out[pixoff + (size_t)(16 + 4 * sub + 1) * 4096] = a1 + (float)shv[1];
    out[pixoff + (size_t)(16 + 4 * sub + 2) * 4096] = a2 + (float)shv[2];
    out[pixoff + (size_t)(16 + 4 * sub + 3) * 4096] = a3 + (float)shv[3];

    // logdet: wave reduce -> LDS partials -> 1 atomic per block
    float tt = tr + __shfl_xor(tr, 1, 64);
    tt += __shfl_xor(tt, 2, 64);
    tt += __shfl_xor(tt, 4, 64);
    tt += __shfl_xor(tt, 8, 64);
    tt += __shfl_xor(tt, 16, 64);
    tt += __shfl_xor(tt, 32, 64);
    float* part = (float*)(smem + 71680);   // past the 128x560 o-tile
    if (lane == 0) part[wave] = tt;
    __syncthreads();
    if (tid == 0) {
      float s = part[0] + part[1] + part[2] + part[3]
              + part[4] + part[5] + part[6] + part[7];
      atomicAdd(&logdet[n], s);
    }
  }
}

extern "C" void kernel_launch(void* const* d_in, const int* in_sizes, int n_in,
                              void* d_out, int out_size, void* d_ws, size_t ws_size,
                              hipStream_t stream) {
  const float* x   = (const float*)d_in[0];
  const float* sc  = (const float*)d_in[1];
  const float* sp  = (const float*)d_in[2];
  const float* rs  = (const float*)d_in[3];
  const float* rsh = (const float*)d_in[4];
  const float* w0  = (const float*)d_in[5];
  const float* b0  = (const float*)d_in[6];
  const float* w1  = (const float*)d_in[7];
  const float* b1  = (const float*)d_in[8];
  const float* w2  = (const float*)d_in[9];
  const float* b2  = (const float*)d_in[10];
  const float* w3  = (const float*)d_in[11];
  const float* b3  = (const float*)d_in[12];

  float* out    = (float*)d_out;
  float* logdet = out + 2097152;
  char* ws = (char*)d_ws;
  f16* x1a = (f16*)(ws + OFF_X1A);
  f16* hA  = (f16*)(ws + OFF_HA);
  f16* hB  = (f16*)(ws + OFF_HB);
  f16* w0p = (f16*)(ws + OFF_W0P);
  f16* w1p = (f16*)(ws + OFF_W1P);
  f16* w2p = (f16*)(ws + OFF_W2P);
  f16* w3p = (f16*)(ws + OFF_W3P);

  setup_k<<<1024, 256, 0, stream>>>(x, w0, w1, w2, w3, logdet, x1a, w0p, w1p, w2p, w3p);
  conv_k<16,  true><<<512, 512, 32768, stream>>>(x1a, w0p, b0, hA);
  conv_k<128, true><<<512, 512, 71808, stream>>>(hA, w1p, b1, hB);
  conv_k<128, true><<<512, 512, 71808, stream>>>(hB, w2p, b2, hA);
  conv3epi_k<<<512, 512, 71808, stream>>>(hA, w3p, b3, x, sc, sp, rs, rsh, out, logdet);
}